// Round 4
// baseline (111.746 us; speedup 1.0000x reference)
//
#include <hip/hip_runtime.h>
#include <hip/hip_bf16.h>
#include <math.h>

#define H 64
#define W 64
#define CIN 128
#define COUT 128
#define BATCH 8
#define NPIX (H*W)      // 4096
#define PXT 32          // pixels per k_deform block
#define AP  136         // vs pitch in bf16
#define RP  36          // red pitch (floats)
#define VSZ (PXT*AP)    // one vs buffer in shorts (4352)

typedef __attribute__((ext_vector_type(8))) short bf16x8;
typedef __attribute__((ext_vector_type(2))) float f32x2;
typedef __attribute__((ext_vector_type(4))) float f32x4;
typedef __attribute__((ext_vector_type(16))) float f32x16;

static __device__ inline short f2bf(float f) {
  union { float f; unsigned u; } v; v.f = f;
  unsigned r = v.u + 0x7FFF + ((v.u >> 16) & 1);   // RNE
  return (short)(r >> 16);
}
// unpack packed bf16x2 word -> f32x2 {lo, hi}; feeds v_pk_fma_f32
static __device__ inline f32x2 bfpair(unsigned u) {
  union { unsigned u; float f; } lo, hi;
  lo.u = u << 16; hi.u = u & 0xffff0000u;
  f32x2 r; r.x = lo.f; r.y = hi.f; return r;
}

// ---------------------------------------------------------------------------
// Kernel 1 (fused prep): [0,2048) transpose NCHW->BHWC bf16 (R14: float4
// loads + uint2 packed stores); [2048,2192) pack wOMs32; [2192,2768) wAs32.
// 32x32x16 A-frag layout: A[m=lane&31][k=(lane>>5)*8+j] (verified R11).
// ---------------------------------------------------------------------------
__global__ __launch_bounds__(256) void k_prep(const float* __restrict__ x,
    short* __restrict__ xbh,
    const float* __restrict__ w_off, const float* __restrict__ w_mod,
    short* __restrict__ wOMs, const float* __restrict__ w_reg,
    short* __restrict__ wAs) {
  __shared__ float tile[32][65];
  int blk = blockIdx.x;
  int t = threadIdx.x;
  if (blk < 2048) {                       // --- transpose ---
    int cg = blk & 3, y = (blk >> 2) & 63, b = blk >> 8;
#pragma unroll
    for (int j = 0; j < 2; ++j) {         // 512 float4s, 2 per thread
      int f = t + j * 256;
      int ci = f >> 4, xi4 = f & 15;
      float4 v = *(const float4*)&x[(((b * CIN + cg * 32 + ci) * H + y) * W) + xi4 * 4];
      *(float4*)&tile[ci][xi4 * 4] = v;
    }
    __syncthreads();
#pragma unroll
    for (int i = 0; i < 2; ++i) {         // 512 items = 64 xi x 8 cig
      int idx = t + i * 256;
      int xi = idx >> 3, cig = idx & 7;
      float f0 = tile[cig * 4 + 0][xi];
      float f1 = tile[cig * 4 + 1][xi];
      float f2 = tile[cig * 4 + 2][xi];
      float f3 = tile[cig * 4 + 3][xi];
      __hip_bfloat162 h01 = __float22bfloat162_rn(make_float2(f0, f1));
      __hip_bfloat162 h23 = __float22bfloat162_rn(make_float2(f2, f3));
      uint2 pk;
      pk.x = *(unsigned*)&h01; pk.y = *(unsigned*)&h23;
      *(uint2*)&xbh[((b * H + y) * W + xi) * CIN + cg * 32 + cig * 4] = pk;
    }
  } else if (blk < 2048 + 144) {          // --- wOMs32 pack ---
    int e = (blk - 2048) * 256 + t;       // tap*4096 + oc*128 + c  (36864)
    int tap = e >> 12, oc = (e >> 7) & 31, c = e & 127;
    float v = 0.f;
    if (oc < 18)      v = w_off[(oc * 128 + c) * 9 + tap];
    else if (oc < 27) v = w_mod[((oc - 18) * 128 + c) * 9 + tap];
    int kstep = c >> 4, g = (c >> 3) & 1, j = c & 7;
    int lane = g * 32 + oc;
    int o = ((tap * 8 + kstep) * 64 + lane) * 8 + j;
    wOMs[o] = f2bf(v);
  } else {                                // --- wAs32 pack ---
    int e = (blk - 2192) * 256 + t;       // tap*16384 + oc*128 + c
    int tap = e >> 14, oc = (e >> 7) & 127, c = e & 127;
    int kstep = c >> 4, g = (c >> 3) & 1, j = c & 7;
    int ms = oc >> 5, m = oc & 31;
    int lane = g * 32 + m;
    int o = (((tap * 8 + kstep) * 4 + ms) * 64 + lane) * 8 + j;
    wAs[o] = f2bf(w_reg[(oc * 128 + c) * 9 + tap]);
  }
}

// ---------------------------------------------------------------------------
// Kernel 2: FUSED offset/mask + deformable conv.  R4 changes vs R3:
//  (1) T14 issue-early: next pair's 8 corner gathers issued BEFORE blending
//      the current pair (depth-1 software pipeline, fully unrolled SSA).
//  (2) T4 counted barrier: main-loop __syncthreads -> s_waitcnt lgkmcnt(0)
//      + raw s_barrier, so prefetched global loads stay in flight across
//      barriers (no vmcnt(0) drain).  Hazard audit in session notes: no
//      global writes in loop; all waves' ds_reads(pi-2) retired at their
//      lgkmcnt(0) of barrier(pi-1), which precedes ds_write(pi).
//  (3) pa4 corner quad read as one ds_read_b64 (uint2) instead of 4x u16.
// Carried from R3: pair-taps (4 vs buffers), pk-FMA blend, static phase-1.
// Layouts unchanged: A[m=lane&31][k=(lane>>5)*8+j] (R11 absmax-verified),
//   C/D row=(r&3)+8*(r>>2)+4*(lane>>5), col=lane&31 [m74/m101].
// ---------------------------------------------------------------------------
__global__ __launch_bounds__(512, 4) void k_deform(const short* __restrict__ xbh,
    const short* __restrict__ wOMs, const float* __restrict__ b_off,
    const float* __restrict__ b_mod, const short* __restrict__ wAs,
    float* __restrict__ out) {
  __shared__ __align__(16) char smem_u[34816];     // red | vs x4 | redE
  __shared__ __align__(16) float  pw[PXT * 9 * 4]; // 4608 B
  __shared__ __align__(16) ushort pa4[PXT * 9 * 4];// 2304 B (pixel-linear)
  float* red  = (float*)smem_u;                    // 31104 B (phase 1)
  short* vs   = (short*)smem_u;                    // 4 x VSZ = 34816 B
  float* redE = (float*)smem_u;                    // 16896 B (epilogue)

  int blk = blockIdx.x;
  int b = blk & 7, tile = blk >> 3;               // XCD swizzle
  int pix0 = tile * PXT;
  int t = threadIdx.x;
  int lane = t & 63;
  int wv = t >> 6;                                // 0..7
  int n32 = lane & 31, g = lane >> 5;

  const short* xbB = xbh + (size_t)b * NPIX * CIN;

  // ===== Phase 1: offset/mask mini-GEMM, statically balanced =====
  // wave wv: all 8 ksteps of tap wv, plus kstep wv of tap 8.  9 MFMA/wave.
  {
    f32x16 accO = {};
    int gp = pix0 + n32;
    int yb = gp >> 6, xb = gp & 63;
    {   // own tap (wv in 0..7)
      int y = yb + wv / 3 - 1, x = xb + wv % 3 - 1;
      int ok = ((unsigned)y < H) && ((unsigned)x < W);
      int lin = ok ? ((y << 6) + x) : 0;
#pragma unroll
      for (int kstep = 0; kstep < 8; ++kstep) {
        bf16x8 a = *(const bf16x8*)&wOMs[((wv * 8 + kstep) * 64 + lane) * 8];
        int c0 = kstep * 16 + g * 8;
        bf16x8 bv = *(const bf16x8*)&xbB[(size_t)lin * CIN + c0];
        if (!ok) bv = (bf16x8){};
        accO = __builtin_amdgcn_mfma_f32_32x32x16_bf16(a, bv, accO, 0, 0, 0);
      }
    }
    {   // shared tap 8 (dy=dx=+1), kstep = wv
      int y = yb + 1, x = xb + 1;
      int ok = (y < H) && (x < W);
      int lin = ok ? ((y << 6) + x) : 0;
      bf16x8 a = *(const bf16x8*)&wOMs[((8 * 8 + wv) * 64 + lane) * 8];
      int c0 = wv * 16 + g * 8;
      bf16x8 bv = *(const bf16x8*)&xbB[(size_t)lin * CIN + c0];
      if (!ok) bv = (bf16x8){};
      accO = __builtin_amdgcn_mfma_f32_32x32x16_bf16(a, bv, accO, 0, 0, 0);
    }
#pragma unroll
    for (int r = 0; r < 16; ++r) {
      int row = (r & 3) + 8 * (r >> 2) + 4 * g;
      if (row < 27) red[wv * (27 * RP) + row * RP + n32] = accO[r];
    }
  }
  __syncthreads();

  // ===== reduce 8 partials + bias + sigmoid -> pw / pa4 =====
  for (int i = t; i < PXT * 9; i += 512) {        // i = p*9 + tap
    int tap = i % 9, p = i / 9;
    float dyv = b_off[2 * tap], dxv = b_off[2 * tap + 1], z = b_mod[tap];
#pragma unroll
    for (int w = 0; w < 8; ++w) {
      const float* rw = red + w * (27 * RP);
      dyv += rw[(2 * tap) * RP + p];
      dxv += rw[(2 * tap + 1) * RP + p];
      z   += rw[(18 + tap) * RP + p];
    }
    float m = 2.f / (1.f + expf(-z));
    int gp = pix0 + p;
    float py = (float)((gp >> 6) - 1 + tap / 3) + dyv;
    float pxx = (float)((gp & 63) - 1 + tap % 3) + dxv;
    float yf = floorf(py), xf = floorf(pxx);
    float wy = py - yf, wx = pxx - xf;
    int y0 = (int)yf, x0 = (int)xf;
    int y1 = y0 + 1, x1 = x0 + 1;
    float vy0 = ((unsigned)y0 < H) ? 1.f : 0.f;
    float vy1 = ((unsigned)y1 < H) ? 1.f : 0.f;
    float vx0 = ((unsigned)x0 < W) ? 1.f : 0.f;
    float vx1 = ((unsigned)x1 < W) ? 1.f : 0.f;
    int y0c = min(max(y0, 0), H - 1), y1c = min(max(y1, 0), H - 1);
    int x0c = min(max(x0, 0), W - 1), x1c = min(max(x1, 0), W - 1);
    *(float4*)&pw[i * 4] = make_float4((1.f - wy) * (1.f - wx) * m * vy0 * vx0,
                                       (1.f - wy) * wx * m * vy0 * vx1,
                                       wy * (1.f - wx) * m * vy1 * vx0,
                                       wy * wx * m * vy1 * vx1);
    pa4[i * 4 + 0] = (ushort)((y0c << 6) + x0c);
    pa4[i * 4 + 1] = (ushort)((y0c << 6) + x1c);
    pa4[i * 4 + 2] = (ushort)((y1c << 6) + x0c);
    pa4[i * 4 + 3] = (ushort)((y1c << 6) + x1c);
  }
  __syncthreads();   // pw/pa visible; red reads done (vs may alias)

  // ===== Phase 2: deformable GEMM, 32x32x16, split-K, PAIRED taps =====
  int ms = wv & 3, ks = wv >> 2;
  int cq = t & 15, ps = t >> 4;           // 8-ch group, pixel (0..31)
  int c0s = cq * 8;

  f32x16 acc = {};

  struct Corners { uint4 a, b, c, d; };
  // issue 4 corner gathers for one tap (loads only — no LDS writes)
  auto issue = [&](int tap) -> Corners {
    int idx = (ps * 9 + tap) * 4;
    uint2 pk = *(const uint2*)&pa4[idx];        // one ds_read_b64
    Corners r;
    r.a = *(const uint4*)&xbB[(int)(pk.x & 0xffffu) * CIN + c0s];
    r.b = *(const uint4*)&xbB[(int)(pk.x >> 16)     * CIN + c0s];
    r.c = *(const uint4*)&xbB[(int)(pk.y & 0xffffu) * CIN + c0s];
    r.d = *(const uint4*)&xbB[(int)(pk.y >> 16)     * CIN + c0s];
    return r;
  };
  // blend 4 corners with pk-fma, pack to bf16, store to vbuf
  auto blendStore = [&](int tap, const Corners& cr, short* vbuf) {
    int idx = (ps * 9 + tap) * 4;
    float4 wq = *(const float4*)&pw[idx];
    uint4 packed;
#pragma unroll
    for (int j = 0; j < 4; ++j) {
      f32x2 s = bfpair(((const unsigned*)&cr.a)[j]) * wq.x;
      s += bfpair(((const unsigned*)&cr.b)[j]) * wq.y;
      s += bfpair(((const unsigned*)&cr.c)[j]) * wq.z;
      s += bfpair(((const unsigned*)&cr.d)[j]) * wq.w;
      __hip_bfloat162 h2 = __float22bfloat162_rn(make_float2(s.x, s.y));
      ((unsigned*)&packed)[j] = *(unsigned*)&h2;
    }
    *(uint4*)&vbuf[ps * AP + c0s] = packed;
  };

  // prologue: pair 0's gathers in flight
  Corners c0 = issue(0), c1 = issue(1);

#pragma unroll
  for (int pi = 0; pi < 5; ++pi) {        // tap pairs {0,1}..{6,7},{8}
    int tp = pi * 2;
    short* vb0 = vs + ((pi & 1) * 2) * VSZ;
    short* vb1 = vb0 + VSZ;

    // --- issue NEXT pair's gathers before consuming current (T14) ---
    Corners n0 = {}, n1 = {};
    if (pi < 4) {
      n0 = issue(tp + 2);
      if (tp + 3 < 9) n1 = issue(tp + 3);
    }

    // --- blend + store current pair ---
    blendStore(tp, c0, vb0);
    if (tp + 1 < 9) blendStore(tp + 1, c1, vb1);

    // --- A frags for both taps ---
    bf16x8 af0[4], af1[4];
#pragma unroll
    for (int i = 0; i < 4; ++i) {
      int kstep = ks * 4 + i;
      af0[i] = *(const bf16x8*)&wAs[(((tp * 8 + kstep) * 4 + ms) * 64 + lane) * 8];
      if (tp + 1 < 9)
        af1[i] = *(const bf16x8*)&wAs[((((tp + 1) * 8 + kstep) * 4 + ms) * 64 + lane) * 8];
    }

    // --- counted barrier: LDS visibility only, vmcnt stays in flight ---
    asm volatile("s_waitcnt lgkmcnt(0)" ::: "memory");
    __builtin_amdgcn_s_barrier();

    // --- MFMA: 8 k-steps of 32x32x16 (4 per tap) ---
#pragma unroll
    for (int i = 0; i < 4; ++i) {
      int kstep = ks * 4 + i;
      int c0r = kstep * 16 + g * 8;
      bf16x8 bfr = *(const bf16x8*)&vb0[n32 * AP + c0r];
      acc = __builtin_amdgcn_mfma_f32_32x32x16_bf16(af0[i], bfr, acc, 0, 0, 0);
    }
    if (tp + 1 < 9) {
#pragma unroll
      for (int i = 0; i < 4; ++i) {
        int kstep = ks * 4 + i;
        int c0r = kstep * 16 + g * 8;
        bf16x8 bfr = *(const bf16x8*)&vb1[n32 * AP + c0r];
        acc = __builtin_amdgcn_mfma_f32_32x32x16_bf16(af1[i], bfr, acc, 0, 0, 0);
      }
    }

    c0 = n0; c1 = n1;
  }

  // ===== epilogue: split-K reduce via redE, then store =====
  __syncthreads();   // full drain; all MFMA vs-reads done before redE aliases
  if (ks == 1) {
#pragma unroll
    for (int r = 0; r < 16; ++r) {
      int row = (r & 3) + 8 * (r >> 2) + 4 * g;
      redE[ms * (32 * 33) + row * 33 + n32] = acc[r];
    }
  }
  __syncthreads();
  if (ks == 0) {
#pragma unroll
    for (int r = 0; r < 16; ++r) {
      int row = (r & 3) + 8 * (r >> 2) + 4 * g;
      float v = acc[r] + redE[ms * (32 * 33) + row * 33 + n32];
      out[(size_t)(b * COUT + ms * 32 + row) * NPIX + pix0 + n32] = v;
    }
  }
}

// ---------------------------------------------------------------------------
extern "C" void kernel_launch(void* const* d_in, const int* in_sizes, int n_in,
                              void* d_out, int out_size, void* d_ws, size_t ws_size,
                              hipStream_t stream) {
  const float* x     = (const float*)d_in[0];
  const float* w_off = (const float*)d_in[1];
  const float* b_off = (const float*)d_in[2];
  const float* w_mod = (const float*)d_in[3];
  const float* b_mod = (const float*)d_in[4];
  const float* w_reg = (const float*)d_in[5];

  short* xbh  = (short*)d_ws;              // 4,194,304 bf16 (8 MB)
  short* wAs  = xbh + 4194304;             //   147,456 bf16 (32x32 swizzled)
  short* wOMs = wAs + 147456;              //    36,864 bf16 (32x32 swizzled)
  float* out  = (float*)d_out;

  k_prep<<<dim3(2768), 256, 0, stream>>>(x, xbh, w_off, w_mod, wOMs,
                                         w_reg, wAs);
  k_deform<<<dim3(NPIX / PXT * BATCH), 512, 0, stream>>>(
      xbh, wOMs, b_off, b_mod, wAs, out);
}

// Round 5
// 110.308 us; speedup vs baseline: 1.0130x; 1.0130x over previous
//
#include <hip/hip_runtime.h>
#include <hip/hip_bf16.h>
#include <math.h>

#define H 64
#define W 64
#define CIN 128
#define COUT 128
#define BATCH 8
#define NPIX (H*W)      // 4096
#define PXT 64          // pixels per k_deform block (one image row)
#define AP  136         // vs pitch in bf16
#define RP  68          // red pitch (floats, 64+4 pad)
#define VSZ (PXT*AP)    // one vs buffer in shorts (8704)

typedef __attribute__((ext_vector_type(8))) short bf16x8;
typedef __attribute__((ext_vector_type(2))) float f32x2;
typedef __attribute__((ext_vector_type(4))) float f32x4;
typedef __attribute__((ext_vector_type(16))) float f32x16;

static __device__ inline short f2bf(float f) {
  union { float f; unsigned u; } v; v.f = f;
  unsigned r = v.u + 0x7FFF + ((v.u >> 16) & 1);   // RNE
  return (short)(r >> 16);
}
// unpack packed bf16x2 word -> f32x2 {lo, hi}; feeds v_pk_fma_f32
static __device__ inline f32x2 bfpair(unsigned u) {
  union { unsigned u; float f; } lo, hi;
  lo.u = u << 16; hi.u = u & 0xffff0000u;
  f32x2 r; r.x = lo.f; r.y = hi.f; return r;
}

// ---------------------------------------------------------------------------
// Kernel 1 (fused prep): [0,2048) transpose NCHW->BHWC bf16 (R14: float4
// loads + uint2 packed stores); [2048,2192) pack wOMs32; [2192,2768) wAs32.
// 32x32x16 A-frag layout: A[m=lane&31][k=(lane>>5)*8+j] (verified R11).
// ---------------------------------------------------------------------------
__global__ __launch_bounds__(256) void k_prep(const float* __restrict__ x,
    short* __restrict__ xbh,
    const float* __restrict__ w_off, const float* __restrict__ w_mod,
    short* __restrict__ wOMs, const float* __restrict__ w_reg,
    short* __restrict__ wAs) {
  __shared__ float tile[32][65];
  int blk = blockIdx.x;
  int t = threadIdx.x;
  if (blk < 2048) {                       // --- transpose ---
    int cg = blk & 3, y = (blk >> 2) & 63, b = blk >> 8;
#pragma unroll
    for (int j = 0; j < 2; ++j) {         // 512 float4s, 2 per thread
      int f = t + j * 256;
      int ci = f >> 4, xi4 = f & 15;
      float4 v = *(const float4*)&x[(((b * CIN + cg * 32 + ci) * H + y) * W) + xi4 * 4];
      *(float4*)&tile[ci][xi4 * 4] = v;
    }
    __syncthreads();
#pragma unroll
    for (int i = 0; i < 2; ++i) {         // 512 items = 64 xi x 8 cig
      int idx = t + i * 256;
      int xi = idx >> 3, cig = idx & 7;
      float f0 = tile[cig * 4 + 0][xi];
      float f1 = tile[cig * 4 + 1][xi];
      float f2 = tile[cig * 4 + 2][xi];
      float f3 = tile[cig * 4 + 3][xi];
      __hip_bfloat162 h01 = __float22bfloat162_rn(make_float2(f0, f1));
      __hip_bfloat162 h23 = __float22bfloat162_rn(make_float2(f2, f3));
      uint2 pk;
      pk.x = *(unsigned*)&h01; pk.y = *(unsigned*)&h23;
      *(uint2*)&xbh[((b * H + y) * W + xi) * CIN + cg * 32 + cig * 4] = pk;
    }
  } else if (blk < 2048 + 144) {          // --- wOMs32 pack ---
    int e = (blk - 2048) * 256 + t;       // tap*4096 + oc*128 + c  (36864)
    int tap = e >> 12, oc = (e >> 7) & 31, c = e & 127;
    float v = 0.f;
    if (oc < 18)      v = w_off[(oc * 128 + c) * 9 + tap];
    else if (oc < 27) v = w_mod[((oc - 18) * 128 + c) * 9 + tap];
    int kstep = c >> 4, g = (c >> 3) & 1, j = c & 7;
    int lane = g * 32 + oc;
    int o = ((tap * 8 + kstep) * 64 + lane) * 8 + j;
    wOMs[o] = f2bf(v);
  } else {                                // --- wAs32 pack ---
    int e = (blk - 2192) * 256 + t;       // tap*16384 + oc*128 + c
    int tap = e >> 14, oc = (e >> 7) & 127, c = e & 127;
    int kstep = c >> 4, g = (c >> 3) & 1, j = c & 7;
    int ms = oc >> 5, m = oc & 31;
    int lane = g * 32 + m;
    int o = (((tap * 8 + kstep) * 4 + ms) * 64 + lane) * 8 + j;
    wAs[o] = f2bf(w_reg[(oc * 128 + c) * 9 + tap]);
  }
}

// ---------------------------------------------------------------------------
// Kernel 2: FUSED offset/mask + deformable conv.  R5: PXT 32 -> 64 (one
// block = one image row).  Halves per-pixel fixed costs: wAs fetch (288 KB
// per block now covers 64 px), wOMs fetch, barriers, phase boundaries;
// every A-frag is reused for two MFMA (px halves 0-31 / 32-63).
//   Phase 1: wave wv = tap wv (8 ksteps x 2 halves) + tap 8 kstep wv x 2.
//            y-bounds wave-uniform (all px same row).  18 MFMA/wave.
//   Phase 2: wave (ms,ks); per tap: sample 2 px/thread -> A-load ->
//            __syncthreads -> 8 MFMA (4 ksteps x 2 halves), dbuf vs.
//   Epilogue: split-K via redE, two sequential 32-px half passes.
// Carried from R3: pk-FMA blend, static balance; R4 pipeline reverted
// (prefetch/counted-barrier measured neutral-negative; ample TLP).
// Layouts unchanged: A[m=lane&31][k=(lane>>5)*8+j] (R11 absmax-verified),
//   C/D row=(r&3)+8*(r>>2)+4*(lane>>5), col=lane&31 [m74/m101].
// LDS: red 57.4KB | vs 2x17KB | redE 16.9KB aliased; +pw 9.2KB +pa4 4.6KB
//   = ~71 KB -> 2 blocks/CU (R2: sufficient).
// ---------------------------------------------------------------------------
__global__ __launch_bounds__(512, 4) void k_deform(const short* __restrict__ xbh,
    const short* __restrict__ wOMs, const float* __restrict__ b_off,
    const float* __restrict__ b_mod, const short* __restrict__ wAs,
    float* __restrict__ out) {
  __shared__ __align__(16) char smem_u[58752];     // red | vs dbuf | redE
  __shared__ __align__(16) float  pw[PXT * 9 * 4]; // 9216 B
  __shared__ __align__(16) ushort pa4[PXT * 9 * 4];// 4608 B (pixel-linear)
  float* red  = (float*)smem_u;                    // 8*27*RP*4 = 58752 B
  short* vs   = (short*)smem_u;                    // 2 x VSZ = 34816 B
  float* redE = (float*)smem_u;                    // 4*32*33*4 = 16896 B

  int blk = blockIdx.x;
  int b = blk & 7, tile = blk >> 3;               // XCD swizzle; tile = row y
  int pix0 = tile * PXT;
  int t = threadIdx.x;
  int lane = t & 63;
  int wv = t >> 6;                                // 0..7
  int n32 = lane & 31, g = lane >> 5;

  const short* xbB = xbh + (size_t)b * NPIX * CIN;

  // ===== Phase 1: offset/mask mini-GEMM, statically balanced =====
  // wave wv: tap wv all 8 ksteps x 2 px-halves, + tap 8 kstep wv x 2.
  {
    f32x16 accO0 = {}, accO1 = {};
    int dy = wv / 3 - 1, dx = wv % 3 - 1;
    int y = tile + dy;
    int okY = ((unsigned)y < H);
    int xA = n32 + dx, xB = 32 + n32 + dx;
    int ok0 = okY && ((unsigned)xA < W);
    int ok1 = okY && ((unsigned)xB < W);
    int lin0 = ok0 ? ((y << 6) + xA) : 0;
    int lin1 = ok1 ? ((y << 6) + xB) : 0;
#pragma unroll
    for (int kstep = 0; kstep < 8; ++kstep) {
      bf16x8 a = *(const bf16x8*)&wOMs[((wv * 8 + kstep) * 64 + lane) * 8];
      int c0 = kstep * 16 + g * 8;
      bf16x8 bv0 = *(const bf16x8*)&xbB[(size_t)lin0 * CIN + c0];
      if (!ok0) bv0 = (bf16x8){};
      accO0 = __builtin_amdgcn_mfma_f32_32x32x16_bf16(a, bv0, accO0, 0, 0, 0);
      bf16x8 bv1 = *(const bf16x8*)&xbB[(size_t)lin1 * CIN + c0];
      if (!ok1) bv1 = (bf16x8){};
      accO1 = __builtin_amdgcn_mfma_f32_32x32x16_bf16(a, bv1, accO1, 0, 0, 0);
    }
    {   // shared tap 8 (dy=dx=+1), kstep = wv
      int y8 = tile + 1;
      int okY8 = (y8 < H);
      int x8A = n32 + 1, x8B = 32 + n32 + 1;
      int ok80 = okY8 && (x8A < W);
      int ok81 = okY8 && (x8B < W);
      int l80 = ok80 ? ((y8 << 6) + x8A) : 0;
      int l81 = ok81 ? ((y8 << 6) + x8B) : 0;
      bf16x8 a8 = *(const bf16x8*)&wOMs[((8 * 8 + wv) * 64 + lane) * 8];
      int c0 = wv * 16 + g * 8;
      bf16x8 bv0 = *(const bf16x8*)&xbB[(size_t)l80 * CIN + c0];
      if (!ok80) bv0 = (bf16x8){};
      accO0 = __builtin_amdgcn_mfma_f32_32x32x16_bf16(a8, bv0, accO0, 0, 0, 0);
      bf16x8 bv1 = *(const bf16x8*)&xbB[(size_t)l81 * CIN + c0];
      if (!ok81) bv1 = (bf16x8){};
      accO1 = __builtin_amdgcn_mfma_f32_32x32x16_bf16(a8, bv1, accO1, 0, 0, 0);
    }
#pragma unroll
    for (int r = 0; r < 16; ++r) {
      int row = (r & 3) + 8 * (r >> 2) + 4 * g;
      if (row < 27) {
        red[wv * (27 * RP) + row * RP + n32]      = accO0[r];
        red[wv * (27 * RP) + row * RP + 32 + n32] = accO1[r];
      }
    }
  }
  __syncthreads();

  // ===== reduce 8 partials + bias + sigmoid -> pw / pa4 =====
  for (int i = t; i < PXT * 9; i += 512) {        // i = p*9 + tap
    int tap = i % 9, p = i / 9;
    float dyv = b_off[2 * tap], dxv = b_off[2 * tap + 1], z = b_mod[tap];
#pragma unroll
    for (int w = 0; w < 8; ++w) {
      const float* rw = red + w * (27 * RP);
      dyv += rw[(2 * tap) * RP + p];
      dxv += rw[(2 * tap + 1) * RP + p];
      z   += rw[(18 + tap) * RP + p];
    }
    float m = 2.f / (1.f + expf(-z));
    int gp = pix0 + p;
    float py = (float)((gp >> 6) - 1 + tap / 3) + dyv;
    float pxx = (float)((gp & 63) - 1 + tap % 3) + dxv;
    float yf = floorf(py), xf = floorf(pxx);
    float wy = py - yf, wx = pxx - xf;
    int y0 = (int)yf, x0 = (int)xf;
    int y1 = y0 + 1, x1 = x0 + 1;
    float vy0 = ((unsigned)y0 < H) ? 1.f : 0.f;
    float vy1 = ((unsigned)y1 < H) ? 1.f : 0.f;
    float vx0 = ((unsigned)x0 < W) ? 1.f : 0.f;
    float vx1 = ((unsigned)x1 < W) ? 1.f : 0.f;
    int y0c = min(max(y0, 0), H - 1), y1c = min(max(y1, 0), H - 1);
    int x0c = min(max(x0, 0), W - 1), x1c = min(max(x1, 0), W - 1);
    *(float4*)&pw[i * 4] = make_float4((1.f - wy) * (1.f - wx) * m * vy0 * vx0,
                                       (1.f - wy) * wx * m * vy0 * vx1,
                                       wy * (1.f - wx) * m * vy1 * vx0,
                                       wy * wx * m * vy1 * vx1);
    pa4[i * 4 + 0] = (ushort)((y0c << 6) + x0c);
    pa4[i * 4 + 1] = (ushort)((y0c << 6) + x1c);
    pa4[i * 4 + 2] = (ushort)((y1c << 6) + x0c);
    pa4[i * 4 + 3] = (ushort)((y1c << 6) + x1c);
  }
  __syncthreads();   // pw/pa visible; red reads done (vs may alias)

  // ===== Phase 2: deformable GEMM, 32x32x16, split-K, 64 px =====
  int ms = wv & 3, ks = wv >> 2;
  int cq = t & 15, ps = t >> 4;           // 8-ch group, pixel (0..31)
  int c0s = cq * 8;

  f32x16 acc0 = {}, acc1 = {};

  // sample one pixel's tap into vbuf: 4 gathers + pk-fma blend + pack
  auto sampleOne = [&](int px, int tap, short* vbuf) {
    int idx = (px * 9 + tap) * 4;
    uint2 pk = *(const uint2*)&pa4[idx];        // one ds_read_b64
    float4 wq = *(const float4*)&pw[idx];
    uint4 u00 = *(const uint4*)&xbB[(int)(pk.x & 0xffffu) * CIN + c0s];
    uint4 u01 = *(const uint4*)&xbB[(int)(pk.x >> 16)     * CIN + c0s];
    uint4 u10 = *(const uint4*)&xbB[(int)(pk.y & 0xffffu) * CIN + c0s];
    uint4 u11 = *(const uint4*)&xbB[(int)(pk.y >> 16)     * CIN + c0s];
    uint4 packed;
#pragma unroll
    for (int j = 0; j < 4; ++j) {
      f32x2 s = bfpair(((const unsigned*)&u00)[j]) * wq.x;
      s += bfpair(((const unsigned*)&u01)[j]) * wq.y;
      s += bfpair(((const unsigned*)&u10)[j]) * wq.z;
      s += bfpair(((const unsigned*)&u11)[j]) * wq.w;
      __hip_bfloat162 h2 = __float22bfloat162_rn(make_float2(s.x, s.y));
      ((unsigned*)&packed)[j] = *(unsigned*)&h2;
    }
    *(uint4*)&vbuf[px * AP + c0s] = packed;
  };

  for (int tap = 0; tap < 9; ++tap) {
    short* vbuf = vs + (tap & 1) * VSZ;

    // --- sample 2 px per thread (halves ps, ps+32) ---
    sampleOne(ps, tap, vbuf);
    sampleOne(ps + 32, tap, vbuf);

    // --- A frags: 4 k-steps, reused across both px halves ---
    bf16x8 af[4];
#pragma unroll
    for (int i = 0; i < 4; ++i) {
      int kstep = ks * 4 + i;
      af[i] = *(const bf16x8*)&wAs[(((tap * 8 + kstep) * 4 + ms) * 64 + lane) * 8];
    }
    __syncthreads();   // vbuf visible; other buffer free

    // --- MFMA: 8 = 4 ksteps x 2 halves ---
#pragma unroll
    for (int i = 0; i < 4; ++i) {
      int kstep = ks * 4 + i;
      int c0r = kstep * 16 + g * 8;
      bf16x8 b0 = *(const bf16x8*)&vbuf[n32 * AP + c0r];
      acc0 = __builtin_amdgcn_mfma_f32_32x32x16_bf16(af[i], b0, acc0, 0, 0, 0);
      bf16x8 b1 = *(const bf16x8*)&vbuf[(32 + n32) * AP + c0r];
      acc1 = __builtin_amdgcn_mfma_f32_32x32x16_bf16(af[i], b1, acc1, 0, 0, 0);
    }
  }

  // ===== epilogue: split-K reduce via redE, two 32-px half passes =====
#pragma unroll
  for (int h = 0; h < 2; ++h) {
    __syncthreads();   // h=0: MFMA vs-reads done; h=1: redE reads done
    if (ks == 1) {
#pragma unroll
      for (int r = 0; r < 16; ++r) {
        int row = (r & 3) + 8 * (r >> 2) + 4 * g;
        float v = (h == 0) ? acc0[r] : acc1[r];
        redE[ms * (32 * 33) + row * 33 + n32] = v;
      }
    }
    __syncthreads();
    if (ks == 0) {
#pragma unroll
      for (int r = 0; r < 16; ++r) {
        int row = (r & 3) + 8 * (r >> 2) + 4 * g;
        float v = ((h == 0) ? acc0[r] : acc1[r])
                + redE[ms * (32 * 33) + row * 33 + n32];
        out[(size_t)(b * COUT + ms * 32 + row) * NPIX + pix0 + h * 32 + n32] = v;
      }
    }
  }
}

// ---------------------------------------------------------------------------
extern "C" void kernel_launch(void* const* d_in, const int* in_sizes, int n_in,
                              void* d_out, int out_size, void* d_ws, size_t ws_size,
                              hipStream_t stream) {
  const float* x     = (const float*)d_in[0];
  const float* w_off = (const float*)d_in[1];
  const float* b_off = (const float*)d_in[2];
  const float* w_mod = (const float*)d_in[3];
  const float* b_mod = (const float*)d_in[4];
  const float* w_reg = (const float*)d_in[5];

  short* xbh  = (short*)d_ws;              // 4,194,304 bf16 (8 MB)
  short* wAs  = xbh + 4194304;             //   147,456 bf16 (32x32 swizzled)
  short* wOMs = wAs + 147456;              //    36,864 bf16 (32x32 swizzled)
  float* out  = (float*)d_out;

  k_prep<<<dim3(2768), 256, 0, stream>>>(x, xbh, w_off, w_mod, wOMs,
                                         w_reg, wAs);
  k_deform<<<dim3(NPIX / PXT * BATCH), 512, 0, stream>>>(
      xbh, wOMs, b_off, b_mod, wAs, out);
}